// Round 1
// baseline (116.070 us; speedup 1.0000x reference)
//
#include <hip/hip_runtime.h>
#include <math.h>

// Problem constants (match reference): M=250000, P=4, K=6, N_MC=64
#define KN 384   // K * N_MC

// Device-global scratch (rewritten every launch; independent of d_ws size)
__device__ float  g_hdr[24];
__device__ float4 g_tab[KN];
__device__ double g_part[1024];

// ---------------------------------------------------------------------------
// Kernel 1: precompute per-(k,n) table + folded constants.
//   g_hdr[2]  = 1/sn
//   g_hdr[3]  = 1/s2
//   g_hdr[8+p]  = exp(log_w[p] + Cint0)        (interior weights, p=0..3)
//   g_hdr[12+p] = I[p]/sn
//   g_hdr[16+k] = exp(log_w[4+k] + Cterm - log 64)  (interface weights)
//   g_tab[k*64+n] = { In/sn, 2G/s2, exp(-log G - G^2/s2), 0 }
// ---------------------------------------------------------------------------
__global__ __launch_bounds__(384) void prep_kernel(
    const float* __restrict__ eps, const float* __restrict__ I,
    const float* __restrict__ W, const float* __restrict__ sb_,
    const float* __restrict__ sn_, const float* __restrict__ d_,
    const float* __restrict__ r_) {
  const int IAc[6] = {0, 0, 0, 1, 1, 2};
  const int IBc[6] = {1, 2, 3, 2, 3, 3};
  int t = threadIdx.x;

  double sb = (double)sb_[0];
  double sn = (double)sn_[0];
  double dd = (double)d_[0];
  double r  = (double)r_[0];
  double rho = tanh(r);
  double s2 = sn * sn * (1.0 - rho);   // = sr^2
  double sr = sqrt(s2);

  // log-softmax denominator over the 10 weights
  double wmax = -1e300;
  for (int j = 0; j < 10; ++j) wmax = fmax(wmax, (double)W[j]);
  double se = 0.0;
  for (int j = 0; j < 10; ++j) se += exp((double)W[j] - wmax);
  double lse = wmax + log(se);

  const double LOG2PI_ = 1.8378770664093453;
  const double LOG2_   = 0.6931471805599453;
  const double LGG32   = -0.12078223763524522;   // log(gamma(1.5))
  const double PI_     = 3.141592653589793;
  double Cterm = -log(sn) - 0.5 * LOG2PI_ - log(sr) - 0.5 * log(PI_);
  double Cint0 = LOG2_ - LGG32 - 3.0 * log(sr) - log(sn) - 0.5 * LOG2PI_;
  float isn = (float)(1.0 / sn);

  if (t == 0) {
    g_hdr[2] = isn;
    g_hdr[3] = (float)(1.0 / s2);
    for (int p = 0; p < 4; ++p) {
      g_hdr[8 + p]  = (float)exp((double)W[p] - lse + Cint0);
      g_hdr[12 + p] = I[p] * isn;
    }
    for (int k = 0; k < 6; ++k)
      g_hdr[16 + k] = (float)exp((double)W[4 + k] - lse + Cterm - log(64.0));
  }

  if (t < KN) {
    int k = t >> 6;
    float Ia = I[IAc[k]], Ib = I[IBc[k]];
    float e  = eps[t];
    float sbf = (float)sb, ddf = (float)dd;
    float x  = e * 2.0f * ddf * sbf - ddf * sbf;
    float y  = x / (1.4142135623730951f * sbf);
    float ey = erff(y);
    float In = (ey + 1.0f) * 0.5f * (Ib - Ia) + Ia;
    float q  = 2.0f * (In - Ia) / (Ib - Ia) - 1.0f;
    float gi = erfinvf(q);
    float G  = (Ib - Ia) / sqrtf((float)(2.0 * PI_) * sbf * sbf) * expf(-gi * gi);
    float4 tt;
    tt.x = In * isn;
    tt.y = (float)(2.0 / s2) * G;
    tt.z = (float)exp(-log((double)G) - (double)G * (double)G / s2);
    tt.w = 0.0f;
    g_tab[t] = tt;
  }
}

// ---------------------------------------------------------------------------
// Kernel 2: main per-point evaluation. 2 points per thread (i0 and i0+H) so
// each ds_read_b128 of the table serves two points. Everything is a direct
// sum of exponentials (no max-shift needed; args bounded in [-64, +18]).
// ---------------------------------------------------------------------------
__global__ __launch_bounds__(256) void main_kernel(
    const float* __restrict__ u, const float* __restrict__ v, int M, int H) {
  __shared__ float4 stab[KN];
  __shared__ float  shc[24];
  __shared__ double red[256];
  int tid = threadIdx.x;

  for (int i = tid; i < KN; i += 256) stab[i] = g_tab[i];
  if (tid < 24) shc[tid] = g_hdr[tid];
  __syncthreads();

  double mysum = 0.0;
  int i0 = blockIdx.x * 256 + tid;
  if (i0 < H) {
    float isn = shc[2], inv_s2 = shc[3];
    int i1 = i0 + H;
    bool has1 = (i1 < M);
    float u0 = u[i0], v0 = v[i0];
    float u1 = has1 ? u[i1] : u0;
    float v1 = has1 ? v[i1] : v0;
    float us0 = u0 * isn, us1 = u1 * isn;
    float g0 = __expf(-v0 * v0 * inv_s2);
    float g1 = __expf(-v1 * v1 * inv_s2);

    // interior phases
    float aint0 = 0.f, aint1 = 0.f;
#pragma unroll
    for (int p = 0; p < 4; ++p) {
      float cI = shc[12 + p], w = shc[8 + p];
      float d0 = us0 - cI, d1 = us1 - cI;
      aint0 = fmaf(w, __expf(-0.5f * d0 * d0), aint0);
      aint1 = fmaf(w, __expf(-0.5f * d1 * d1), aint1);
    }

    // interface rows
    float aface0 = 0.f, aface1 = 0.f;
#pragma unroll 1
    for (int k = 0; k < 6; ++k) {
      const float4* tk = stab + (k << 6);
      float S0 = 0.f, S1 = 0.f;
#pragma unroll 8
      for (int n = 0; n < 64; ++n) {
        float4 tt = tk[n];
        // point 0: exp(z-h) - exp(-z-h), h = 0.5*du^2
        float z0  = v0 * tt.y;
        float du0 = us0 - tt.x;
        float a0  = -0.5f * du0;
        float e0p = __expf(fmaf(du0, a0, z0));
        float e0m = __expf(fmaf(du0, a0, -z0));
        S0 = fmaf(tt.z, e0p - e0m, S0);
        // point 1
        float z1  = v1 * tt.y;
        float du1 = us1 - tt.x;
        float a1  = -0.5f * du1;
        float e1p = __expf(fmaf(du1, a1, z1));
        float e1m = __expf(fmaf(du1, a1, -z1));
        S1 = fmaf(tt.z, e1p - e1m, S1);
      }
      float wk = shc[16 + k];
      aface0 = fmaf(wk, S0, aface0);
      aface1 = fmaf(wk, S1, aface1);
    }

    // acc = v*g*(v*aint + aface)  ==  sum_j w_j exp(log_p_j)
    float acc0 = v0 * g0 * fmaf(v0, aint0, aface0);
    float acc1 = v1 * g1 * fmaf(v1, aint1, aface1);
    mysum = (double)__logf(acc0);
    if (has1) mysum += (double)__logf(acc1);
  }

  // block reduction (deterministic, no atomics)
  red[tid] = mysum;
  __syncthreads();
  for (int s = 128; s > 0; s >>= 1) {
    if (tid < s) red[tid] += red[tid + s];
    __syncthreads();
  }
  if (tid == 0) g_part[blockIdx.x] = red[0];
}

// ---------------------------------------------------------------------------
// Kernel 3: reduce block partials, write -sum/M
// ---------------------------------------------------------------------------
__global__ __launch_bounds__(1024) void finish_kernel(float* __restrict__ out,
                                                      int nb, int M) {
  __shared__ double red[1024];
  int t = threadIdx.x;
  double s = 0.0;
  for (int i = t; i < nb; i += 1024) s += g_part[i];
  red[t] = s;
  __syncthreads();
  for (int k = 512; k > 0; k >>= 1) {
    if (t < k) red[t] += red[t + k];
    __syncthreads();
  }
  if (t == 0) out[0] = (float)(-red[0] / (double)M);
}

extern "C" void kernel_launch(void* const* d_in, const int* in_sizes, int n_in,
                              void* d_out, int out_size, void* d_ws, size_t ws_size,
                              hipStream_t stream) {
  const float* u   = (const float*)d_in[0];
  const float* v   = (const float*)d_in[1];
  const float* eps = (const float*)d_in[2];
  const float* I   = (const float*)d_in[3];
  const float* W   = (const float*)d_in[4];
  const float* sb  = (const float*)d_in[5];
  const float* sn  = (const float*)d_in[6];
  const float* dd  = (const float*)d_in[7];
  const float* r   = (const float*)d_in[8];
  int M = in_sizes[0];
  int H = (M + 1) / 2;
  int nb = (H + 255) / 256;   // 489 for M=250000; g_part holds up to 1024

  hipLaunchKernelGGL(prep_kernel, dim3(1), dim3(384), 0, stream,
                     eps, I, W, sb, sn, dd, r);
  hipLaunchKernelGGL(main_kernel, dim3(nb), dim3(256), 0, stream, u, v, M, H);
  hipLaunchKernelGGL(finish_kernel, dim3(1), dim3(1024), 0, stream,
                     (float*)d_out, nb, M);
}

// Round 2
// 110.001 us; speedup vs baseline: 1.0552x; 1.0552x over previous
//
#include <hip/hip_runtime.h>
#include <math.h>

// BIMM2D: M=250000 points, P=4 interior phases, K=6 interface pairs, N_MC=64
#define KN 384   // K * N_MC
#define TPB 256

// Device-global scratch. g_ctr is module-init to 0 and self-restored by the
// last block every launch -> graph-replay safe, no dependence on d_ws poison.
__device__ double g_part[1024];
__device__ int    g_ctr = 0;

// Single fused kernel:
//   prelude  : every thread computes folded scalar constants (float, ~200 cy);
//              block cooperatively builds the 384-entry (k,n) table in LDS.
//   main     : 1 point/thread, direct sum of exponentials (args in [-64, +14],
//              no max-shift needed anywhere).
//   epilogue : block tree-reduction -> g_part[bid]; last-block-done pattern
//              does the fixed-order final reduction (bit-deterministic).
__global__ __launch_bounds__(TPB) void fused_kernel(
    const float* __restrict__ u, const float* __restrict__ v,
    const float* __restrict__ eps, const float* __restrict__ I,
    const float* __restrict__ W, const float* __restrict__ sb_,
    const float* __restrict__ sn_, const float* __restrict__ d_,
    const float* __restrict__ r_, float* __restrict__ out,
    int M, int nb) {
  __shared__ float4 stab[KN];
  __shared__ double red[TPB];
  __shared__ int    slast;
  const int tid = threadIdx.x;
  const int i   = blockIdx.x * TPB + tid;

  // hoist the point loads to overlap global latency with the prelude
  float uu = 0.f, vv = 1.f;
  if (i < M) { uu = u[i]; vv = v[i]; }

  // ---- folded constants (uniform across threads; float = faithful to ref) ----
  const float sb  = sb_[0];
  const float sn  = sn_[0];
  const float dd  = d_[0];
  const float rho = tanhf(r_[0]);
  const float s2  = sn * sn * (1.f - rho);      // sr^2
  const float sr  = sqrtf(s2);
  const float isn = 1.f / sn;
  const float inv_s2 = 1.f / s2;

  float wmax = W[0];
  for (int j = 1; j < 10; ++j) wmax = fmaxf(wmax, W[j]);
  float se = 0.f;
  for (int j = 0; j < 10; ++j) se += expf(W[j] - wmax);
  const float lse = wmax + logf(se);

  const float LOG2PI_ = 1.8378770664093453f;
  const float LOG2_   = 0.6931471805599453f;
  const float LGG32   = -0.12078223763524522f;  // log(gamma(1.5))
  const float LOGPI_  = 1.1447298858494002f;
  const float Cterm = -logf(sn) - 0.5f * LOG2PI_ - logf(sr) - 0.5f * LOGPI_;
  const float Cint0 = LOG2_ - LGG32 - 3.f * logf(sr) - logf(sn) - 0.5f * LOG2PI_;

  float wint[4], cI[4];
#pragma unroll
  for (int p = 0; p < 4; ++p) {
    wint[p] = expf(W[p] - lse + Cint0);
    cI[p]   = I[p] * isn;
  }

  // ---- per-(k,n) table into LDS ----
  // stab[t] = { In/sn, 2G/s2, wk * exp(-G^2/s2)/G, 0 }, wk folds softmax w,
  // e^Cterm and the 1/N_MC of the MC logsumexp.
  const int IAc[6] = {0, 0, 0, 1, 1, 2};
  const int IBc[6] = {1, 2, 3, 2, 3, 3};
  for (int t = tid; t < KN; t += TPB) {
    const int k = t >> 6;
    const float Ia = I[IAc[k]], Ib = I[IBc[k]];
    const float wk = expf(W[4 + k] - lse + Cterm) * (1.0f / 64.0f);
    const float e  = eps[t];
    const float x  = e * 2.f * dd * sb - dd * sb;
    const float y  = x / (1.4142135623730951f * sb);
    const float In = (erff(y) + 1.f) * 0.5f * (Ib - Ia) + Ia;
    const float q  = 2.f * (In - Ia) / (Ib - Ia) - 1.f;
    const float gi = erfinvf(q);
    const float G  = (Ib - Ia) * 0.3989422804014327f / sb * expf(-gi * gi);
    float4 tt;
    tt.x = In * isn;
    tt.y = 2.f * inv_s2 * G;
    tt.z = wk * expf(-G * G * inv_s2) / G;
    tt.w = 0.f;
    stab[t] = tt;
  }
  __syncthreads();

  // ---- main per-point evaluation ----
  double mysum = 0.0;
  if (i < M) {
    const float us = uu * isn;
    const float g  = __expf(-vv * vv * inv_s2);

    float aint = 0.f;
#pragma unroll
    for (int p = 0; p < 4; ++p) {
      const float d0 = us - cI[p];
      aint = fmaf(wint[p], __expf(-0.5f * d0 * d0), aint);
    }

    float aface = 0.f;
#pragma unroll 8
    for (int n = 0; n < KN; ++n) {
      const float4 tt = stab[n];           // wave-uniform addr -> LDS broadcast
      const float z  = vv * tt.y;
      const float du = us - tt.x;
      const float m  = -0.5f * du;
      const float e1 = __expf(fmaf(du, m, z));    //  z - h
      const float e2 = __expf(fmaf(du, m, -z));   // -z - h
      aface = fmaf(tt.z, e1 - e2, aface);
    }

    const float acc = vv * g * fmaf(vv, aint, aface);
    mysum = (double)__logf(acc);
  }

  // ---- block reduction ----
  red[tid] = mysum;
  __syncthreads();
  for (int s = TPB / 2; s > 0; s >>= 1) {
    if (tid < s) red[tid] += red[tid + s];
    __syncthreads();
  }
  if (tid == 0)
    __hip_atomic_store(&g_part[blockIdx.x], red[0], __ATOMIC_RELAXED,
                       __HIP_MEMORY_SCOPE_AGENT);

  // ---- last-block-done final reduction (deterministic: fixed order) ----
  if (tid == 0) {
    const int c = __hip_atomic_fetch_add(&g_ctr, 1, __ATOMIC_ACQ_REL,
                                         __HIP_MEMORY_SCOPE_AGENT);
    slast = (c == nb - 1) ? 1 : 0;
  }
  __syncthreads();
  if (slast) {
    double s = 0.0;
    for (int j = tid; j < nb; j += TPB)
      s += __hip_atomic_load(&g_part[j], __ATOMIC_RELAXED,
                             __HIP_MEMORY_SCOPE_AGENT);
    red[tid] = s;
    __syncthreads();
    for (int k2 = TPB / 2; k2 > 0; k2 >>= 1) {
      if (tid < k2) red[tid] += red[tid + k2];
      __syncthreads();
    }
    if (tid == 0) {
      out[0] = (float)(-red[0] / (double)M);
      __hip_atomic_store(&g_ctr, 0, __ATOMIC_RELAXED,
                         __HIP_MEMORY_SCOPE_AGENT);  // restore for next replay
    }
  }
}

extern "C" void kernel_launch(void* const* d_in, const int* in_sizes, int n_in,
                              void* d_out, int out_size, void* d_ws, size_t ws_size,
                              hipStream_t stream) {
  const float* u   = (const float*)d_in[0];
  const float* v   = (const float*)d_in[1];
  const float* eps = (const float*)d_in[2];
  const float* I   = (const float*)d_in[3];
  const float* W   = (const float*)d_in[4];
  const float* sb  = (const float*)d_in[5];
  const float* sn  = (const float*)d_in[6];
  const float* dd  = (const float*)d_in[7];
  const float* r   = (const float*)d_in[8];
  const int M  = in_sizes[0];
  const int nb = (M + TPB - 1) / TPB;   // 977 for M=250000 (g_part holds 1024)

  hipLaunchKernelGGL(fused_kernel, dim3(nb), dim3(TPB), 0, stream,
                     u, v, eps, I, W, sb, sn, dd, r, (float*)d_out, M, nb);
}